// Round 1
// baseline (982.160 us; speedup 1.0000x reference)
//
#include <hip/hip_runtime.h>
#include <hip/hip_bf16.h>

// HetNetwork 3-layer MLP (gfx950), fp32 I/O, bf16 MFMA compute.
// [B,1024] -> 256 -> 256 -> 256, B=131072.
// Split structure: kernel A = GEMM1 (K=1024, 2/3 of FLOPs) at high occupancy,
// h1 round-trips global as bf16 (67 MB ~ 21 us HBM); kernel B = fused GEMM2+3.
// R3 changes (theory: latency-bound, not roofline — 104 TF / 0.81 TB/s):
//  - gemm23: 512 thr / 8 waves (2 rg x 4 slabs, acc[2][4]) -> 16 waves/CU
//    (was 8), weight staging via wcur/wnxt register double-buffer (zero-stall
//    ds_write), GEMM2->GEMM3 weight handoff hidden under h2 act epilogue.
//  - gemm1: x loads issued as one early batch; weights in the same
//    wcur/wnxt reg pipeline. Math & layouts bit-identical to verified run.

typedef __bf16 bf16;
typedef __bf16 bf16x8 __attribute__((ext_vector_type(8)));
typedef float  f32x4  __attribute__((ext_vector_type(4)));

#define BATCH 131072
#define K1    1024
#define HDIM  256

// ---- per-column heterogeneous activation (exact forms) ----
__device__ __forceinline__ float het_act(float z, int aid) {
    if (aid == 0) return fmaxf(z, 0.0f);
    if (aid == 1) {
        float zc = fminf(fmaxf(z, -20.0f), 20.0f);
        float e = __expf(-2.0f * zc);
        return (1.0f - e) / (1.0f + e);                // tanh
    }
    if (aid == 2) return 0.5f * z * (1.0f + erff(z * 0.70710678118654752f)); // exact gelu
    return 1.0f / (1.0f + __expf(-z));                 // sigmoid
}

// ---- prep: dst[n][k] = (bf16)src[k][n] ----
__global__ void prep_w(const float* __restrict__ src, bf16* __restrict__ dst,
                       int total, int kshift, int N) {
    int i = blockIdx.x * blockDim.x + threadIdx.x;
    if (i >= total) return;
    int n = i >> kshift;
    int k = i & ((1 << kshift) - 1);
    dst[i] = (bf16)src[(size_t)k * N + n];
}

// =====================================================================
// Kernel A: h1 = act(x @ W1 + b1)  [fp32 in, bf16 out]
// 128 rows x 256 cols per block, 512 threads = 8 waves (2 row-groups x 4 slabs)
// BK=64 -> 16 k-iterations, 32 MFMA per wave per barrier pair.
// =====================================================================
#define RMA 128
#define BKA 64
#define ASTR 72     // 64+8 pad: row step 144B = 36 banks -> 2-way (free)
#define HSTR 264    // h1-tile store stride

__global__ __launch_bounds__(512, 4) void gemm1_kernel(
    const float* __restrict__ x,    // [B][1024]
    const bf16*  __restrict__ wt1,  // [256][1024] bf16(W1^T)
    const float* __restrict__ b1,
    const int*   __restrict__ aid1,
    bf16* __restrict__ h1)          // [B][256] bf16
{
    // union: staging (as 18432 + ws 36864 = 55296 B) vs h1-tile (67584 B)
    __shared__ __align__(16) char smem[RMA * HSTR * 2];   // 67584 B
    bf16 (*as)[ASTR] = (bf16(*)[ASTR])smem;               // [128][72]
    bf16 (*ws)[ASTR] = (bf16(*)[ASTR])(smem + RMA * ASTR * 2); // [256][72]
    bf16 (*hout)[HSTR] = (bf16(*)[HSTR])smem;             // [128][264]

    const int tid  = threadIdx.x;
    const int lane = tid & 63;
    const int wave = tid >> 6;       // 0..7
    const int rg   = wave >> 2;      // row-group 0/1 (64 rows each)
    const int slab = wave & 3;       // 64-col slab
    const int l15  = lane & 15;
    const int quad = lane >> 4;
    const size_t row0 = (size_t)blockIdx.x * RMA;

    // per-thread staging coords (same mapping as verified kernel)
    const int xr0 = tid >> 3;        // x rows 0..63   (p=0)
    const int xr1 = xr0 + 64;        // x rows 64..127 (p=1)
    const int xq  = tid & 7;
    const int wn0 = tid >> 3;        // weight row base, +64 per chunk
    const int wq  = tid & 7;

    f32x4 acc[4][4];
    #pragma unroll
    for (int i = 0; i < 4; ++i)
        #pragma unroll
        for (int j = 0; j < 4; ++j)
            acc[i][j] = (f32x4){0.f, 0.f, 0.f, 0.f};

    // weight register double-buffer: prologue load for kt=0
    bf16x8 wcur[4], wnxt[4];
    #pragma unroll
    for (int p = 0; p < 4; ++p)
        wcur[p] = *(const bf16x8*)(wt1 + (size_t)(wn0 + p * 64) * K1 + wq * 8);

    for (int kt = 0; kt < K1 / BKA; ++kt) {
        const int k0 = kt * BKA;
        // 1) issue ALL x loads first (HBM stream — longest latency)
        const float* xp0 = x + (row0 + xr0) * K1 + k0 + xq * 8;
        const float* xp1 = x + (row0 + xr1) * K1 + k0 + xq * 8;
        float4 f0a = *(const float4*)xp0;
        float4 f0b = *(const float4*)(xp0 + 4);
        float4 f1a = *(const float4*)xp1;
        float4 f1b = *(const float4*)(xp1 + 4);
        // 2) issue next-iteration weight loads (L2-resident after warmup)
        const int k0n = (kt + 1 < K1 / BKA) ? k0 + BKA : 0;  // dummy reload at tail
        #pragma unroll
        for (int p = 0; p < 4; ++p)
            wnxt[p] = *(const bf16x8*)(wt1 + (size_t)(wn0 + p * 64) * K1 + k0n + wq * 8);
        // 3) ds_write current weights — regs already resident, zero stall
        #pragma unroll
        for (int p = 0; p < 4; ++p)
            *(bf16x8*)&ws[wn0 + p * 64][wq * 8] = wcur[p];
        // 4) convert + ds_write x (first wait on this iteration's loads)
        {
            bf16x8 va, vb;
            va[0] = (bf16)f0a.x; va[1] = (bf16)f0a.y; va[2] = (bf16)f0a.z; va[3] = (bf16)f0a.w;
            va[4] = (bf16)f0b.x; va[5] = (bf16)f0b.y; va[6] = (bf16)f0b.z; va[7] = (bf16)f0b.w;
            *(bf16x8*)&as[xr0][xq * 8] = va;
            vb[0] = (bf16)f1a.x; vb[1] = (bf16)f1a.y; vb[2] = (bf16)f1a.z; vb[3] = (bf16)f1a.w;
            vb[4] = (bf16)f1b.x; vb[5] = (bf16)f1b.y; vb[6] = (bf16)f1b.z; vb[7] = (bf16)f1b.w;
            *(bf16x8*)&as[xr1][xq * 8] = vb;
        }
        __syncthreads();
        #pragma unroll
        for (int s = 0; s < 2; ++s) {
            bf16x8 afr[4];
            #pragma unroll
            for (int i = 0; i < 4; ++i)
                afr[i] = *(const bf16x8*)&as[rg * 64 + i * 16 + l15][s * 32 + quad * 8];
            #pragma unroll
            for (int j = 0; j < 4; ++j) {
                bf16x8 bfr = *(const bf16x8*)&ws[slab * 64 + j * 16 + l15][s * 32 + quad * 8];
                #pragma unroll
                for (int i = 0; i < 4; ++i)
                    acc[i][j] = __builtin_amdgcn_mfma_f32_16x16x32_bf16(afr[i], bfr, acc[i][j], 0, 0, 0);
            }
        }
        __syncthreads();
        #pragma unroll
        for (int p = 0; p < 4; ++p) wcur[p] = wnxt[p];
    }

    // epilogue: bias + act -> bf16 h1-tile in LDS (aliases staging; safe: all
    // frag ds_reads retired before the loop's final barrier)
    #pragma unroll
    for (int j = 0; j < 4; ++j) {
        int col = slab * 64 + j * 16 + l15;
        float bias = b1[col];
        int aid = aid1[col];
        #pragma unroll
        for (int i = 0; i < 4; ++i)
            #pragma unroll
            for (int r = 0; r < 4; ++r) {
                int row = rg * 64 + i * 16 + quad * 4 + r;
                hout[row][col] = (bf16)het_act(acc[i][j][r] + bias, aid);
            }
    }
    __syncthreads();
    // coalesced bf16x8 store: 128x256 = 4096 chunk8, 8/thread
    #pragma unroll
    for (int p = 0; p < 8; ++p) {
        int c = tid + p * 512;
        int r = c >> 5, q = c & 31;
        *(bf16x8*)(h1 + (row0 + r) * HDIM + q * 8) = *(const bf16x8*)&hout[r][q * 8];
    }
}

// =====================================================================
// Kernel B: out = act(h1 @ W2 + b2) @ Wout + bout   [bf16 in, fp32 out]
// 64 rows/block, 512 threads = 8 waves (2 row-groups x 4 col slabs).
// 16 waves/CU (2 blocks); weights via wcur/wnxt register pipeline.
// =====================================================================
#define RMB 64
#define BKB 64
#define BSTR 72
#define BHSTR 264

__global__ __launch_bounds__(512, 4) void gemm23_kernel(
    const bf16*  __restrict__ h1,   // [B][256] bf16
    const bf16*  __restrict__ wt2,  // [256][256] bf16(W2^T)
    const float* __restrict__ b2,
    const bf16*  __restrict__ wt3,  // [256][256] bf16(Wout^T)
    const float* __restrict__ bout,
    const int*   __restrict__ aid2,
    float* __restrict__ out)        // [B][256] fp32
{
    __shared__ __align__(16) bf16 hs[RMB][BHSTR];   // 33792 B (h1 tile, then h2)
    __shared__ __align__(16) bf16 ws[HDIM][BSTR];   // 36864 B

    const int tid  = threadIdx.x;
    const int lane = tid & 63;
    const int wave = tid >> 6;       // 0..7
    const int rg   = wave >> 2;      // row-group 0/1 (32 rows each)
    const int slab = wave & 3;       // 64-col slab
    const int l15  = lane & 15;
    const int quad = lane >> 4;
    const size_t row0 = (size_t)blockIdx.x * RMB;
    const int wn0 = tid >> 3;        // weight row base, +64 per chunk
    const int wq  = tid & 7;

    // issue h1-tile loads (HBM) and wt2 prologue (L2) as one batch
    bf16x8 hreg[4];
    #pragma unroll
    for (int p = 0; p < 4; ++p) {
        int c = tid + p * 512;
        int r = c >> 5, q = c & 31;
        hreg[p] = *(const bf16x8*)(h1 + (row0 + r) * HDIM + q * 8);
    }
    bf16x8 wcur[4], wnxt[4];
    #pragma unroll
    for (int p = 0; p < 4; ++p)
        wcur[p] = *(const bf16x8*)(wt2 + (size_t)(wn0 + p * 64) * HDIM + wq * 8);
    // write h1 tile to LDS
    #pragma unroll
    for (int p = 0; p < 4; ++p) {
        int c = tid + p * 512;
        int r = c >> 5, q = c & 31;
        *(bf16x8*)&hs[r][q * 8] = hreg[p];
    }

    f32x4 acc[2][4];

    // ---- GEMM2 ----
    #pragma unroll
    for (int i = 0; i < 2; ++i)
        #pragma unroll
        for (int j = 0; j < 4; ++j)
            acc[i][j] = (f32x4){0.f, 0.f, 0.f, 0.f};

    #pragma unroll
    for (int kt = 0; kt < HDIM / BKB; ++kt) {
        const int k0 = kt * BKB;
        // ds_write current weights (regs resident, zero stall)
        #pragma unroll
        for (int p = 0; p < 4; ++p)
            *(bf16x8*)&ws[wn0 + p * 64][wq * 8] = wcur[p];
        // prefetch next slice; last iteration hands off to GEMM3's wt3 k0=0
        const int   k0n  = (kt < 3) ? k0 + BKB : 0;
        const bf16* wsrc = (kt < 3) ? wt2 : wt3;
        #pragma unroll
        for (int p = 0; p < 4; ++p)
            wnxt[p] = *(const bf16x8*)(wsrc + (size_t)(wn0 + p * 64) * HDIM + k0n + wq * 8);
        __syncthreads();   // also orders the h1-tile (kt=0) writes
        #pragma unroll
        for (int s = 0; s < 2; ++s) {
            bf16x8 afr[2];
            #pragma unroll
            for (int i = 0; i < 2; ++i)
                afr[i] = *(const bf16x8*)&hs[rg * 32 + i * 16 + l15][k0 + s * 32 + quad * 8];
            #pragma unroll
            for (int j = 0; j < 4; ++j) {
                bf16x8 bfr = *(const bf16x8*)&ws[slab * 64 + j * 16 + l15][s * 32 + quad * 8];
                #pragma unroll
                for (int i = 0; i < 2; ++i)
                    acc[i][j] = __builtin_amdgcn_mfma_f32_16x16x32_bf16(afr[i], bfr, acc[i][j], 0, 0, 0);
            }
        }
        __syncthreads();
        #pragma unroll
        for (int p = 0; p < 4; ++p) wcur[p] = wnxt[p];
    }
    // epilogue: h2 = act(. + b2) -> hs (all hs reads retired before final barrier;
    // pure VALU — overlaps the in-flight wt3 prefetch)
    #pragma unroll
    for (int j = 0; j < 4; ++j) {
        int col = slab * 64 + j * 16 + l15;
        float bias = b2[col];
        int aid = aid2[col];
        #pragma unroll
        for (int i = 0; i < 2; ++i)
            #pragma unroll
            for (int r = 0; r < 4; ++r) {
                int row = rg * 32 + i * 16 + quad * 4 + r;
                hs[row][col] = (bf16)het_act(acc[i][j][r] + bias, aid);
            }
    }

    // ---- GEMM3 ----
    #pragma unroll
    for (int i = 0; i < 2; ++i)
        #pragma unroll
        for (int j = 0; j < 4; ++j)
            acc[i][j] = (f32x4){0.f, 0.f, 0.f, 0.f};

    #pragma unroll
    for (int kt = 0; kt < HDIM / BKB; ++kt) {
        const int k0 = kt * BKB;
        #pragma unroll
        for (int p = 0; p < 4; ++p)
            *(bf16x8*)&ws[wn0 + p * 64][wq * 8] = wcur[p];
        const int k0n = (kt < 3) ? k0 + BKB : 0;   // tail: dummy reload
        #pragma unroll
        for (int p = 0; p < 4; ++p)
            wnxt[p] = *(const bf16x8*)(wt3 + (size_t)(wn0 + p * 64) * HDIM + k0n + wq * 8);
        __syncthreads();   // orders h2 writes before reads
        #pragma unroll
        for (int s = 0; s < 2; ++s) {
            bf16x8 afr[2];
            #pragma unroll
            for (int i = 0; i < 2; ++i)
                afr[i] = *(const bf16x8*)&hs[rg * 32 + i * 16 + l15][k0 + s * 32 + quad * 8];
            #pragma unroll
            for (int j = 0; j < 4; ++j) {
                bf16x8 bfr = *(const bf16x8*)&ws[slab * 64 + j * 16 + l15][s * 32 + quad * 8];
                #pragma unroll
                for (int i = 0; i < 2; ++i)
                    acc[i][j] = __builtin_amdgcn_mfma_f32_16x16x32_bf16(afr[i], bfr, acc[i][j], 0, 0, 0);
            }
        }
        __syncthreads();
        #pragma unroll
        for (int p = 0; p < 4; ++p) wcur[p] = wnxt[p];
    }
    // epilogue: fp32 store (lanes 0-15 contiguous 64B runs)
    #pragma unroll
    for (int j = 0; j < 4; ++j) {
        int col = slab * 64 + j * 16 + l15;
        float bias = bout[col];
        #pragma unroll
        for (int i = 0; i < 2; ++i)
            #pragma unroll
            for (int r = 0; r < 4; ++r) {
                int row = rg * 32 + i * 16 + quad * 4 + r;
                out[(row0 + row) * HDIM + col] = acc[i][j][r] + bias;
            }
    }
}

// =====================================================================
// Fallback: round-2 fused kernel (used only if ws_size can't hold h1)
// =====================================================================
#define FRM 64
#define FAPAD 40
#define FHPAD 264

__global__ __launch_bounds__(256, 2) void hetnet_fused(
    const float* __restrict__ x, const bf16* __restrict__ wt1, const float* __restrict__ b1,
    const bf16* __restrict__ wt2, const float* __restrict__ b2,
    const bf16* __restrict__ wt3, const float* __restrict__ bout,
    const int* __restrict__ aid1, const int* __restrict__ aid2, float* __restrict__ out)
{
    __shared__ __align__(16) bf16 hs[FRM][FHPAD];
    __shared__ __align__(16) bf16 as[FRM][FAPAD];
    __shared__ __align__(16) bf16 ws[HDIM][FAPAD];

    const int tid = threadIdx.x, lane = tid & 63, wave = tid >> 6;
    const int l15 = lane & 15, quad = lane >> 4;
    const size_t row0 = (size_t)blockIdx.x * FRM;
    f32x4 acc[4][4];

    #pragma unroll
    for (int i = 0; i < 4; ++i)
        #pragma unroll
        for (int j = 0; j < 4; ++j) acc[i][j] = (f32x4){0.f,0.f,0.f,0.f};
    for (int kt = 0; kt < K1 / 32; ++kt) {
        const int k0 = kt * 32;
        { int r = tid >> 2, q = tid & 3;
          const float* xp = x + (row0 + r) * K1 + k0 + q * 8;
          float4 f0 = *(const float4*)xp; float4 f1 = *(const float4*)(xp + 4);
          bf16x8 v; v[0]=(bf16)f0.x; v[1]=(bf16)f0.y; v[2]=(bf16)f0.z; v[3]=(bf16)f0.w;
          v[4]=(bf16)f1.x; v[5]=(bf16)f1.y; v[6]=(bf16)f1.z; v[7]=(bf16)f1.w;
          *(bf16x8*)&as[r][q * 8] = v; }
        #pragma unroll
        for (int p = 0; p < 4; ++p) {
            int c = tid + p * 256, n = c >> 2, q = c & 3;
            *(bf16x8*)&ws[n][q * 8] = *(const bf16x8*)(wt1 + (size_t)n * K1 + k0 + q * 8);
        }
        __syncthreads();
        bf16x8 afr[4];
        #pragma unroll
        for (int i = 0; i < 4; ++i) afr[i] = *(const bf16x8*)&as[i*16 + l15][quad*8];
        #pragma unroll
        for (int j = 0; j < 4; ++j) {
            bf16x8 bfr = *(const bf16x8*)&ws[wave*64 + j*16 + l15][quad*8];
            #pragma unroll
            for (int i = 0; i < 4; ++i)
                acc[i][j] = __builtin_amdgcn_mfma_f32_16x16x32_bf16(afr[i], bfr, acc[i][j], 0,0,0);
        }
        __syncthreads();
    }
    #pragma unroll
    for (int j = 0; j < 4; ++j) {
        int col = wave*64 + j*16 + l15; float bias = b1[col]; int aid = aid1[col];
        #pragma unroll
        for (int i = 0; i < 4; ++i)
            #pragma unroll
            for (int r = 0; r < 4; ++r)
                hs[i*16 + quad*4 + r][col] = (bf16)het_act(acc[i][j][r] + bias, aid);
    }
    const bf16* wts[2] = {wt2, wt3};
    for (int g = 0; g < 2; ++g) {
        #pragma unroll
        for (int i = 0; i < 4; ++i)
            #pragma unroll
            for (int j = 0; j < 4; ++j) acc[i][j] = (f32x4){0.f,0.f,0.f,0.f};
        for (int kt = 0; kt < HDIM / 32; ++kt) {
            const int k0 = kt * 32;
            #pragma unroll
            for (int p = 0; p < 4; ++p) {
                int c = tid + p * 256, n = c >> 2, q = c & 3;
                *(bf16x8*)&ws[n][q * 8] = *(const bf16x8*)(wts[g] + (size_t)n * HDIM + k0 + q * 8);
            }
            __syncthreads();
            bf16x8 afr[4];
            #pragma unroll
            for (int i = 0; i < 4; ++i) afr[i] = *(const bf16x8*)&hs[i*16 + l15][k0 + quad*8];
            #pragma unroll
            for (int j = 0; j < 4; ++j) {
                bf16x8 bfr = *(const bf16x8*)&ws[wave*64 + j*16 + l15][quad*8];
                #pragma unroll
                for (int i = 0; i < 4; ++i)
                    acc[i][j] = __builtin_amdgcn_mfma_f32_16x16x32_bf16(afr[i], bfr, acc[i][j], 0,0,0);
            }
            __syncthreads();
        }
        if (g == 0) {
            #pragma unroll
            for (int j = 0; j < 4; ++j) {
                int col = wave*64 + j*16 + l15; float bias = b2[col]; int aid = aid2[col];
                #pragma unroll
                for (int i = 0; i < 4; ++i)
                    #pragma unroll
                    for (int r = 0; r < 4; ++r)
                        hs[i*16 + quad*4 + r][col] = (bf16)het_act(acc[i][j][r] + bias, aid);
            }
        } else {
            #pragma unroll
            for (int j = 0; j < 4; ++j) {
                int col = wave*64 + j*16 + l15; float bias = bout[col];
                #pragma unroll
                for (int i = 0; i < 4; ++i)
                    #pragma unroll
                    for (int r = 0; r < 4; ++r)
                        out[(row0 + i*16 + quad*4 + r) * HDIM + col] = acc[i][j][r] + bias;
            }
        }
    }
}

extern "C" void kernel_launch(void* const* d_in, const int* in_sizes, int n_in,
                              void* d_out, int out_size, void* d_ws, size_t ws_size,
                              hipStream_t stream) {
    const float* x    = (const float*)d_in[0];
    const float* W1   = (const float*)d_in[1];
    const float* b1   = (const float*)d_in[2];
    const float* W2   = (const float*)d_in[3];
    const float* b2   = (const float*)d_in[4];
    const float* Wout = (const float*)d_in[5];
    const float* bout = (const float*)d_in[6];
    const int*   aid1 = (const int*)d_in[7];
    const int*   aid2 = (const int*)d_in[8];
    float* out = (float*)d_out;

    bf16* wt1 = (bf16*)d_ws;                       // 256*1024
    bf16* wt2 = wt1 + 256 * 1024;                  // 256*256
    bf16* wt3 = wt2 + 256 * 256;                   // 256*256
    bf16* h1  = wt3 + 256 * 256;                   // 131072*256 bf16 = 67.1 MB

    const size_t need = (size_t)(256 * 1024 + 2 * 256 * 256) * 2
                      + (size_t)BATCH * HDIM * 2;

    prep_w<<<(K1 * HDIM + 255) / 256, 256, 0, stream>>>(W1, wt1, K1 * HDIM, 10, HDIM);
    prep_w<<<(HDIM * HDIM + 255) / 256, 256, 0, stream>>>(W2, wt2, HDIM * HDIM, 8, HDIM);
    prep_w<<<(HDIM * HDIM + 255) / 256, 256, 0, stream>>>(Wout, wt3, HDIM * HDIM, 8, HDIM);

    if (ws_size >= need) {
        gemm1_kernel<<<BATCH / RMA, 512, 0, stream>>>(x, wt1, b1, aid1, h1);
        gemm23_kernel<<<BATCH / RMB, 512, 0, stream>>>(h1, wt2, b2, wt3, bout, aid2, out);
    } else {
        hetnet_fused<<<BATCH / FRM, 256, 0, stream>>>(x, wt1, b1, wt2, b2, wt3, bout,
                                                      aid1, aid2, out);
    }
}

// Round 2
// 952.053 us; speedup vs baseline: 1.0316x; 1.0316x over previous
//
#include <hip/hip_runtime.h>
#include <hip/hip_bf16.h>

// HetNetwork 3-layer MLP (gfx950), fp32 I/O, bf16 MFMA compute.
// [B,1024] -> 256 -> 256 -> 256, B=131072.
// R4: SINGLE fused kernel. Theory from R3-null (+0.7% despite 2x occupancy):
// bottleneck is the 2-barrier-per-K-step LDS-staging cadence (vmcnt(0) drain
// at every barrier, 32 MFMA between), not wave count. Changes:
//  - Weights consumed as B-fragments DIRECTLY from global (L2-resident,
//    wt1=512KB, wt2/wt3=128KB) -> zero LDS weight staging, zero staging
//    barriers. Fragment addresses byte-identical to the staged values of the
//    verified R2/R3 kernels -> numerics unchanged.
//  - x tile double-buffered in LDS -> ONE barrier per K-step (16 total).
//  - GEMM2+GEMM3: h1/h2 tiles live in LDS, read-only during K-loops ->
//    ZERO barriers inside the K-loops (128 MFMA between barriers).
//  - No h1 global round-trip (saves 134 MB traffic + a full kernel).
// LDS 67584 B -> 2 blocks/CU (16 waves). ws need drops to 786 KB.

typedef __bf16 bf16;
typedef __bf16 bf16x8 __attribute__((ext_vector_type(8)));
typedef float  f32x4  __attribute__((ext_vector_type(4)));

#define BATCH 131072
#define K1    1024
#define HDIM  256

// ---- per-column heterogeneous activation (exact forms) ----
__device__ __forceinline__ float het_act(float z, int aid) {
    if (aid == 0) return fmaxf(z, 0.0f);
    if (aid == 1) {
        float zc = fminf(fmaxf(z, -20.0f), 20.0f);
        float e = __expf(-2.0f * zc);
        return (1.0f - e) / (1.0f + e);                // tanh
    }
    if (aid == 2) return 0.5f * z * (1.0f + erff(z * 0.70710678118654752f)); // exact gelu
    return 1.0f / (1.0f + __expf(-z));                 // sigmoid
}

// ---- prep: dst[n][k] = (bf16)src[k][n] ----
__global__ void prep_w(const float* __restrict__ src, bf16* __restrict__ dst,
                       int total, int kshift, int N) {
    int i = blockIdx.x * blockDim.x + threadIdx.x;
    if (i >= total) return;
    int n = i >> kshift;
    int k = i & ((1 << kshift) - 1);
    dst[i] = (bf16)src[(size_t)k * N + n];
}

// =====================================================================
// Fused kernel: 128 rows/block, 512 threads = 8 waves (2 rg x 4 slabs).
// Each wave owns a 64-row x 64-col output sub-tile (acc[4][4]).
// =====================================================================
#define RM   128
#define ASTR 72     // 64+8 pad: row step 144 B -> 2-way bank alias (free)
#define HSTR 264    // h-tile stride: row step 528 B -> 2-way alias (free)

__global__ __launch_bounds__(512, 4) void hetnet_one(
    const float* __restrict__ x,     // [B][1024]
    const bf16*  __restrict__ wt1,   // [256][1024] bf16(W1^T)
    const float* __restrict__ b1,  const int* __restrict__ aid1,
    const bf16*  __restrict__ wt2,   // [256][256]  bf16(W2^T)
    const float* __restrict__ b2,  const int* __restrict__ aid2,
    const bf16*  __restrict__ wt3,   // [256][256]  bf16(Wout^T)
    const float* __restrict__ bout,
    float* __restrict__ out)         // [B][256] fp32
{
    // union: x staging dbuf (2 x 128 x 72 bf16 = 36864 B) vs h tile (67584 B)
    __shared__ __align__(16) char smem[RM * HSTR * 2];   // 67584 B
    bf16 (*as)[ASTR] = (bf16(*)[ASTR])smem;              // [256][72]: rows 0-127 buf0, 128-255 buf1
    bf16 (*hs)[HSTR] = (bf16(*)[HSTR])smem;              // [128][264]

    const int tid  = threadIdx.x;
    const int lane = tid & 63;
    const int wave = tid >> 6;       // 0..7
    const int rg   = wave >> 2;      // row-group 0/1 (64 rows each)
    const int slab = wave & 3;       // 64-col slab
    const int l15  = lane & 15;
    const int quad = lane >> 4;
    const size_t row0 = (size_t)blockIdx.x * RM;

    // x staging coords: thread stages 32 B of row xr and row xr+64
    const int xr = tid >> 3;         // 0..63
    const int xq = tid & 7;
    const float* xbase = x + (row0 + xr) * K1 + xq * 8;

    f32x4 acc[4][4];
    #pragma unroll
    for (int i = 0; i < 4; ++i)
        #pragma unroll
        for (int j = 0; j < 4; ++j)
            acc[i][j] = (f32x4){0.f, 0.f, 0.f, 0.f};

    // ---------------- Phase 1: acc = x @ W1 (K=1024) ----------------
    {   // prologue: stage k-tile 0 into buf0
        float4 f0 = *(const float4*)(xbase);
        float4 f1 = *(const float4*)(xbase + 4);
        float4 f2 = *(const float4*)(xbase + (size_t)64 * K1);
        float4 f3 = *(const float4*)(xbase + (size_t)64 * K1 + 4);
        bf16x8 va, vb;
        va[0]=(bf16)f0.x; va[1]=(bf16)f0.y; va[2]=(bf16)f0.z; va[3]=(bf16)f0.w;
        va[4]=(bf16)f1.x; va[5]=(bf16)f1.y; va[6]=(bf16)f1.z; va[7]=(bf16)f1.w;
        vb[0]=(bf16)f2.x; vb[1]=(bf16)f2.y; vb[2]=(bf16)f2.z; vb[3]=(bf16)f2.w;
        vb[4]=(bf16)f3.x; vb[5]=(bf16)f3.y; vb[6]=(bf16)f3.z; vb[7]=(bf16)f3.w;
        *(bf16x8*)&as[xr][xq * 8] = va;
        *(bf16x8*)&as[64 + xr][xq * 8] = vb;
    }
    __syncthreads();

    for (int kt = 0; kt < K1 / 64; ++kt) {
        const int buf  = (kt & 1) * RM;
        const int nbuf = RM - buf;
        // issue next k-tile x loads early (consumed after MFMA -> HBM latency hidden)
        float4 f0, f1, f2, f3;
        if (kt < 15) {
            const float* xp = xbase + (kt + 1) * 64;
            f0 = *(const float4*)(xp);
            f1 = *(const float4*)(xp + 4);
            f2 = *(const float4*)(xp + (size_t)64 * K1);
            f3 = *(const float4*)(xp + (size_t)64 * K1 + 4);
        }
        // 32 MFMA; B-fragments straight from L2 (same values the old kernel staged)
        #pragma unroll
        for (int s = 0; s < 2; ++s) {
            bf16x8 afr[4];
            #pragma unroll
            for (int i = 0; i < 4; ++i)
                afr[i] = *(const bf16x8*)&as[buf + rg * 64 + i * 16 + l15][s * 32 + quad * 8];
            #pragma unroll
            for (int j = 0; j < 4; ++j) {
                bf16x8 bfr = *(const bf16x8*)(wt1
                    + (size_t)(slab * 64 + j * 16 + l15) * K1 + kt * 64 + s * 32 + quad * 8);
                #pragma unroll
                for (int i = 0; i < 4; ++i)
                    acc[i][j] = __builtin_amdgcn_mfma_f32_16x16x32_bf16(afr[i], bfr, acc[i][j], 0, 0, 0);
            }
        }
        // convert + stage into the other buffer (no reader conflict), ONE barrier
        if (kt < 15) {
            bf16x8 va, vb;
            va[0]=(bf16)f0.x; va[1]=(bf16)f0.y; va[2]=(bf16)f0.z; va[3]=(bf16)f0.w;
            va[4]=(bf16)f1.x; va[5]=(bf16)f1.y; va[6]=(bf16)f1.z; va[7]=(bf16)f1.w;
            vb[0]=(bf16)f2.x; vb[1]=(bf16)f2.y; vb[2]=(bf16)f2.z; vb[3]=(bf16)f2.w;
            vb[4]=(bf16)f3.x; vb[5]=(bf16)f3.y; vb[6]=(bf16)f3.z; vb[7]=(bf16)f3.w;
            *(bf16x8*)&as[nbuf + xr][xq * 8] = va;
            *(bf16x8*)&as[nbuf + 64 + xr][xq * 8] = vb;
        }
        __syncthreads();
    }

    // phase-1 epilogue: h1 = act(acc + b1) -> hs (aliases staging; all staging
    // reads retired at the loop's final barrier)
    #pragma unroll
    for (int j = 0; j < 4; ++j) {
        const int col = slab * 64 + j * 16 + l15;
        const float bias = b1[col];
        const int aid = aid1[col];
        #pragma unroll
        for (int i = 0; i < 4; ++i)
            #pragma unroll
            for (int r = 0; r < 4; ++r)
                hs[rg * 64 + i * 16 + quad * 4 + r][col] = (bf16)het_act(acc[i][j][r] + bias, aid);
    }
    __syncthreads();

    // ---------------- Phase 2: acc = h1 @ W2 (K=256) — no barriers in loop ----
    #pragma unroll
    for (int i = 0; i < 4; ++i)
        #pragma unroll
        for (int j = 0; j < 4; ++j)
            acc[i][j] = (f32x4){0.f, 0.f, 0.f, 0.f};

    #pragma unroll
    for (int kt = 0; kt < HDIM / 64; ++kt) {
        #pragma unroll
        for (int s = 0; s < 2; ++s) {
            bf16x8 afr[4];
            #pragma unroll
            for (int i = 0; i < 4; ++i)
                afr[i] = *(const bf16x8*)&hs[rg * 64 + i * 16 + l15][kt * 64 + s * 32 + quad * 8];
            #pragma unroll
            for (int j = 0; j < 4; ++j) {
                bf16x8 bfr = *(const bf16x8*)(wt2
                    + (size_t)(slab * 64 + j * 16 + l15) * HDIM + kt * 64 + s * 32 + quad * 8);
                #pragma unroll
                for (int i = 0; i < 4; ++i)
                    acc[i][j] = __builtin_amdgcn_mfma_f32_16x16x32_bf16(afr[i], bfr, acc[i][j], 0, 0, 0);
            }
        }
    }
    __syncthreads();   // all h1 reads retired before h2 overwrites hs

    // phase-2 epilogue: h2 = act(acc + b2) -> hs
    #pragma unroll
    for (int j = 0; j < 4; ++j) {
        const int col = slab * 64 + j * 16 + l15;
        const float bias = b2[col];
        const int aid = aid2[col];
        #pragma unroll
        for (int i = 0; i < 4; ++i)
            #pragma unroll
            for (int r = 0; r < 4; ++r)
                hs[rg * 64 + i * 16 + quad * 4 + r][col] = (bf16)het_act(acc[i][j][r] + bias, aid);
    }
    __syncthreads();

    // ---------------- Phase 3: out = h2 @ Wout + bout — no barriers in loop ----
    #pragma unroll
    for (int i = 0; i < 4; ++i)
        #pragma unroll
        for (int j = 0; j < 4; ++j)
            acc[i][j] = (f32x4){0.f, 0.f, 0.f, 0.f};

    #pragma unroll
    for (int kt = 0; kt < HDIM / 64; ++kt) {
        #pragma unroll
        for (int s = 0; s < 2; ++s) {
            bf16x8 afr[4];
            #pragma unroll
            for (int i = 0; i < 4; ++i)
                afr[i] = *(const bf16x8*)&hs[rg * 64 + i * 16 + l15][kt * 64 + s * 32 + quad * 8];
            #pragma unroll
            for (int j = 0; j < 4; ++j) {
                bf16x8 bfr = *(const bf16x8*)(wt3
                    + (size_t)(slab * 64 + j * 16 + l15) * HDIM + kt * 64 + s * 32 + quad * 8);
                #pragma unroll
                for (int i = 0; i < 4; ++i)
                    acc[i][j] = __builtin_amdgcn_mfma_f32_16x16x32_bf16(afr[i], bfr, acc[i][j], 0, 0, 0);
            }
        }
    }

    // final epilogue: fp32 store (lanes 0-15 give contiguous 64 B runs)
    #pragma unroll
    for (int j = 0; j < 4; ++j) {
        const int col = slab * 64 + j * 16 + l15;
        const float bias = bout[col];
        #pragma unroll
        for (int i = 0; i < 4; ++i)
            #pragma unroll
            for (int r = 0; r < 4; ++r) {
                const int row = rg * 64 + i * 16 + quad * 4 + r;
                out[(row0 + row) * HDIM + col] = acc[i][j][r] + bias;
            }
    }
}

extern "C" void kernel_launch(void* const* d_in, const int* in_sizes, int n_in,
                              void* d_out, int out_size, void* d_ws, size_t ws_size,
                              hipStream_t stream) {
    const float* x    = (const float*)d_in[0];
    const float* W1   = (const float*)d_in[1];
    const float* b1   = (const float*)d_in[2];
    const float* W2   = (const float*)d_in[3];
    const float* b2   = (const float*)d_in[4];
    const float* Wout = (const float*)d_in[5];
    const float* bout = (const float*)d_in[6];
    const int*   aid1 = (const int*)d_in[7];
    const int*   aid2 = (const int*)d_in[8];
    float* out = (float*)d_out;

    bf16* wt1 = (bf16*)d_ws;                       // 256*1024
    bf16* wt2 = wt1 + 256 * 1024;                  // 256*256
    bf16* wt3 = wt2 + 256 * 256;                   // 256*256  (total 786 KB)

    prep_w<<<(K1 * HDIM + 255) / 256, 256, 0, stream>>>(W1, wt1, K1 * HDIM, 10, HDIM);
    prep_w<<<(HDIM * HDIM + 255) / 256, 256, 0, stream>>>(W2, wt2, HDIM * HDIM, 8, HDIM);
    prep_w<<<(HDIM * HDIM + 255) / 256, 256, 0, stream>>>(Wout, wt3, HDIM * HDIM, 8, HDIM);

    hetnet_one<<<BATCH / RM, 512, 0, stream>>>(x, wt1, b1, aid1, wt2, b2, aid2,
                                               wt3, bout, out);
}